// Round 16
// baseline (94.321 us; speedup 1.0000x reference)
//
#include <hip/hip_runtime.h>
#include <float.h>

// Chamfer distance, fp32, N=M=16384 — R16 DIAGNOSTIC: R15 with the LDS
// sweep executed TWICE (idempotent min; index-wrapped so loads re-issue and
// nothing CSEs). Purpose: cd_main has been invisible in rocprof top-5 since
// R7 (the harness's 40us 268MB workspace-poison fills outrank it), and 5
// structural hypotheses (occupancy, pipeline depth, L2 vs LDS, traffic,
// min count) all came back null at cd_main ~30-34us vs a ~7-15us pipe
// model. Doubling the sweep lifts cd_main past the fills -> its MfmaUtil /
// VALUBusy / bank-conflict counters surface, and the scaling factor
// separates throughput-bound (~2x dur) from fixed-overhead (~1.5x).
// Decision table pre-registered in the session journal; R17 = single sweep
// + the indicated fix.
//
// Math (unchanged, absmax 0.0 across R7-R15): d = u.t + |t|^2 + |q|^2,
// u=-2q, 2-level bf16 split, K=14 of 16:
//   k:      0..2     3..5     6..7+8   9..11    12 13
//   A:    uh(xyz)  ul(xyz)  uh(xyz)  ul(xyz)    1  1
//   B:    th(xyz)  th(xyz)  tl(xyz)  tl(xyz)   wh wl
// Layouts (guide §3, m74/m101): A row=lane&31, k=8*(lane>>5)+j; B col=
// lane&31; D col=lane&31, row=(reg&3)+8*(reg>>2)+4*(lane>>5).

#define NPTS 16384
constexpr int QPB   = 512;                // queries per block (64 per wave)
constexpr int NQB   = NPTS / QPB;         // 32 query-blocks per direction
constexpr int NFRAG = NPTS / 32;          // 512 B-frags per point set
constexpr int FPC   = 64;                 // frags per chunk (64KB LDS)
constexpr int NTC   = NFRAG / FPC;        // 8 target chunks
constexpr int FRAG_SHORTS = 512;          // 64 lanes x 8 bf16 = 1KB per frag
constexpr int SET_SHORTS  = NFRAG * FRAG_SHORTS;   // 512 KB per set

typedef float f32x16 __attribute__((ext_vector_type(16)));
typedef short bf16x8 __attribute__((ext_vector_type(8)));

__device__ inline ushort bf16rne(float f) {
    uint u = __float_as_uint(f);
    u += 0x7fff + ((u >> 16) & 1);        // round-to-nearest-even
    return (ushort)(u >> 16);
}
__device__ inline float bf2f(ushort h) { return __uint_as_float(((uint)h) << 16); }

// Split both point sets into B-fragment layout: bt[set][frag][lane][8 bf16].
// Also zeroes the output accumulator for cd_finish's atomic adds.
__global__ __launch_bounds__(512) void cd_prep(const float* __restrict__ gt,
                                               const float* __restrict__ gen,
                                               short* __restrict__ bt,
                                               float* __restrict__ out) {
    if (blockIdx.x == 0 && threadIdx.x == 0) out[0] = 0.0f;

    const int t   = blockIdx.x * 512 + threadIdx.x;   // 0..65535
    const int set = t >> 15;                          // 0: gt, 1: gen
    const int rem = t & 32767;
    const int h   = rem >> 14;                        // k-group 0/1
    const int p   = rem & (NPTS - 1);                 // point index
    const float* __restrict__ src = set ? gen : gt;

    const float x = src[3 * p + 0], y = src[3 * p + 1], z = src[3 * p + 2];
    const ushort hx = bf16rne(x), hy = bf16rne(y), hz = bf16rne(z);
    const ushort lx = bf16rne(x - bf2f(hx));
    const ushort ly = bf16rne(y - bf2f(hy));
    const ushort lz = bf16rne(z - bf2f(hz));
    const float w = fmaf(x, x, fmaf(y, y, z * z));
    const ushort wh = bf16rne(w), wl = bf16rne(w - bf2f(wh));

    bf16x8 v;
    if (h == 0)
        v = (bf16x8){(short)hx, (short)hy, (short)hz, (short)hx,
                     (short)hy, (short)hz, (short)lx, (short)ly};
    else
        v = (bf16x8){(short)lz, (short)lx, (short)ly, (short)lz,
                     (short)wh, (short)wl, (short)0, (short)0};
    *(bf16x8*)(bt + set * SET_SHORTS + (p >> 5) * FRAG_SHORTS
               + (h * 32 + (p & 31)) * 8) = v;
}

__global__ __launch_bounds__(512, 2) void cd_main(const float* __restrict__ gt,
                                                  const float* __restrict__ gen,
                                                  const short* __restrict__ bt,
                                                  float* __restrict__ part2) {
    const int tc  = blockIdx.y & (NTC - 1);        // target chunk 0..7
    const int dir = blockIdx.y >> 3;               // 0: gt->gen, 1: gen->gt
    const float* __restrict__ Q = dir ? gen : gt;
    const short* __restrict__ BT = bt + (dir ? 0 : SET_SHORTS)   // opposite set
                                 + tc * FPC * FRAG_SHORTS;

    __shared__ short FRsh[FPC * FRAG_SHORTS];      // 64 KB: this block's chunk

    const int tid  = threadIdx.x;
    const int lane = tid & 63;
    const int wave = __builtin_amdgcn_readfirstlane(tid >> 6);

    // ---- Stage the chunk once: 64KB linear copy, 8 x 16B per thread. ----
    #pragma unroll
    for (int k = 0; k < 8; ++k) {
        const int idx = k * 512 + tid;             // 0..4095 (16B units)
        ((bf16x8*)FRsh)[idx] = ((const bf16x8*)BT)[idx];
    }

    // ---- 2 A-frags per wave (each wave owns 64 DISTINCT queries). ----
    const int arow = lane & 31, kg = lane >> 5;
    const int qw = blockIdx.x * QPB + wave * 64;   // this wave's query base
    bf16x8 a[2];
    #pragma unroll
    for (int f = 0; f < 2; ++f) {
        const int q = qw + f * 32 + arow;
        const float x = Q[3 * q + 0], y = Q[3 * q + 1], z = Q[3 * q + 2];
        const float ux = -2.f * x, uy = -2.f * y, uz = -2.f * z;
        const ushort hx = bf16rne(ux), hy = bf16rne(uy), hz = bf16rne(uz);
        const ushort lx = bf16rne(ux - bf2f(hx));
        const ushort ly = bf16rne(uy - bf2f(hy));
        const ushort lz = bf16rne(uz - bf2f(hz));
        if (kg == 0)
            a[f] = (bf16x8){(short)hx, (short)hy, (short)hz, (short)lx,
                            (short)ly, (short)lz, (short)hx, (short)hy};
        else
            a[f] = (bf16x8){(short)hz, (short)lx, (short)ly, (short)lz,
                            (short)0x3f80, (short)0x3f80, (short)0, (short)0};
    }

    f32x16 mm0 = (f32x16)(FLT_MAX), mm1 = (f32x16)(FLT_MAX);
    const f32x16 zc = (f32x16)(0.f);

    __syncthreads();                               // chunk staged

    // ---- DIAGNOSTIC 2x sweep: 2*FPC steps, frag index wraps at FPC.
    //      Pass 2 recomputes identical d's and re-mins them (idempotent;
    //      loads re-issue, nothing folds). Inner body is byte-identical
    //      to R15 so the counters decompose R15's real mix. ----
    const short* rb = FRsh + lane * 8;
    for (int s = 0; s < 2 * FPC; s += 2) {
        const int f2 = s & (FPC - 1);
        const bf16x8 b0 = *(const bf16x8*)(rb + f2 * FRAG_SHORTS);
        const bf16x8 b1 = *(const bf16x8*)(rb + (f2 + 1) * FRAG_SHORTS);
        const f32x16 d00 = __builtin_amdgcn_mfma_f32_32x32x16_bf16(a[0], b0, zc, 0, 0, 0);
        const f32x16 d01 = __builtin_amdgcn_mfma_f32_32x32x16_bf16(a[0], b1, zc, 0, 0, 0);
        #pragma unroll
        for (int i = 0; i < 16; ++i)
            mm0[i] = fminf(fminf(d00[i], d01[i]), mm0[i]);
        const f32x16 d10 = __builtin_amdgcn_mfma_f32_32x32x16_bf16(a[1], b0, zc, 0, 0, 0);
        const f32x16 d11 = __builtin_amdgcn_mfma_f32_32x32x16_bf16(a[1], b1, zc, 0, 0, 0);
        #pragma unroll
        for (int i = 0; i < 16; ++i)
            mm1[i] = fminf(fminf(d10[i], d11[i]), mm1[i]);
    }

    // ---- Cross-lane min over the 32 target-cols; write partials direct. ----
    float* pd = part2 + (size_t)blockIdx.y * NPTS + qw;   // [dir*8+tc][q]
    #pragma unroll
    for (int i = 0; i < 16; ++i) {
        float v0 = mm0[i], v1 = mm1[i];
        #pragma unroll
        for (int off = 1; off <= 16; off <<= 1) {
            v0 = fminf(v0, __shfl_xor(v0, off, 64));
            v1 = fminf(v1, __shfl_xor(v1, off, 64));
        }
        const int row = (i & 3) + 8 * (i >> 2) + 4 * kg;
        if ((lane & 31) == 0) {
            pd[row]      = v0;                     // frag 0: query qw+row
            pd[32 + row] = v1;                     // frag 1: query qw+32+row
        }
    }
}

// min over the 8 chunk-partials, add |q|^2, global sum.
__global__ __launch_bounds__(512) void cd_finish(const float* __restrict__ gt,
                                                 const float* __restrict__ gen,
                                                 const float* __restrict__ part2,
                                                 float* __restrict__ out) {
    const int t   = blockIdx.x * 512 + threadIdx.x;   // 0..32767
    const int dir = t >> 14;
    const int q   = t & (NPTS - 1);
    const float* __restrict__ Q = dir ? gen : gt;

    float m = FLT_MAX;
    #pragma unroll
    for (int tc = 0; tc < NTC; ++tc)
        m = fminf(m, part2[(size_t)(dir * NTC + tc) * NPTS + q]);
    const float x = Q[3 * q + 0], y = Q[3 * q + 1], z = Q[3 * q + 2];
    float v = m + fmaf(x, x, fmaf(y, y, z * z));

    #pragma unroll
    for (int off = 32; off > 0; off >>= 1) v += __shfl_down(v, off, 64);
    __shared__ float ws[8];
    const int lane = threadIdx.x & 63, w = threadIdx.x >> 6;
    if (lane == 0) ws[w] = v;
    __syncthreads();
    if (threadIdx.x == 0) {
        float s = 0.0f;
        #pragma unroll
        for (int i = 0; i < 8; ++i) s += ws[i];
        atomicAdd(out, s * (1.0f / (float)NPTS));
    }
}

extern "C" void kernel_launch(void* const* d_in, const int* in_sizes, int n_in,
                              void* d_out, int out_size, void* d_ws, size_t ws_size,
                              hipStream_t stream) {
    const float* gt  = (const float*)d_in[0];
    const float* gen = (const float*)d_in[1];
    short* bt        = (short*)d_ws;                            // 2 x 512 KB
    float* part2     = (float*)((short*)d_ws + 2 * SET_SHORTS); // 16 x 16384 f32
    float* out       = (float*)d_out;

    cd_prep<<<128, 512, 0, stream>>>(gt, gen, bt, out);
    dim3 grid(NQB, NTC * 2);                       // 32 x 16 = 512 blocks
    cd_main<<<grid, 512, 0, stream>>>(gt, gen, bt, part2);
    cd_finish<<<64, 512, 0, stream>>>(gt, gen, part2, out);
}

// Round 17
// 77.681 us; speedup vs baseline: 1.2142x; 1.2142x over previous
//
#include <hip/hip_runtime.h>
#include <float.h>

// Chamfer distance, fp32, N=M=16384 — R17: fused split+sweep, 2 kernels.
//
// R16 diagnostic (2x sweep) decomposed cd_main: sweep ~14us (2x its ~7-8us
// overlapped pipe floor; dependency-serialized), fixed ~12.4us ~= 3 kernel
// launches x ~4us. Per the pre-registered decision table, R17 cuts fixed
// cost: cd_prep is FUSED into cd_main (each block splits its own 2048-pt
// chunk into LDS B-frag layout; redundant across the 32 q-blocks sharing a
// chunk but only ~0.1us VALU vs a saved launch + bt HBM round trip). bt
// workspace eliminated; 3 kernels -> 2. Sweep/epilogue/finish identical to
// R15 (absmax 0.0 lineage).
//
// Math (absmax 0.0, R7-R16): d = u.t + |t|^2 + |q|^2, u=-2q, 2-level bf16
// split, full product expansion in K=14 of 16:
//   k:      0..2     3..5     6..7+8   9..11    12 13
//   A:    uh(xyz)  ul(xyz)  uh(xyz)  ul(xyz)    1  1
//   B:    th(xyz)  th(xyz)  tl(xyz)  tl(xyz)   wh wl
// Layouts (guide §3, m74/m101): A row=lane&31, k=8*(lane>>5)+j; B col=
// lane&31; D col=lane&31, row=(reg&3)+8*(reg>>2)+4*(lane>>5).

#define NPTS 16384
constexpr int QPB   = 512;                // queries per block (64 per wave)
constexpr int NQB   = NPTS / QPB;         // 32 query-blocks per direction
constexpr int TPC   = 2048;               // targets per chunk
constexpr int NTC   = NPTS / TPC;         // 8 target chunks
constexpr int FPC   = TPC / 32;           // 64 frags per chunk (64KB LDS)
constexpr int FRAG_SHORTS = 512;          // 64 lane-slots x 8 bf16 = 1KB/frag

typedef float  f32x4  __attribute__((ext_vector_type(4)));
typedef float  f32x16 __attribute__((ext_vector_type(16)));
typedef short  bf16x8 __attribute__((ext_vector_type(8)));

__device__ inline ushort bf16rne(float f) {
    uint u = __float_as_uint(f);
    u += 0x7fff + ((u >> 16) & 1);        // round-to-nearest-even
    return (ushort)(u >> 16);
}
__device__ inline float bf2f(ushort h) { return __uint_as_float(((uint)h) << 16); }

__global__ __launch_bounds__(512, 2) void cd_main(const float* __restrict__ gt,
                                                  const float* __restrict__ gen,
                                                  float* __restrict__ part2,
                                                  float* __restrict__ out) {
    const int tc  = blockIdx.y & (NTC - 1);        // target chunk 0..7
    const int dir = blockIdx.y >> 3;               // 0: gt->gen, 1: gen->gt
    const float* __restrict__ Q = dir ? gen : gt;
    const float* __restrict__ T = dir ? gt : gen;  // opposite set

    if (blockIdx.x == 0 && blockIdx.y == 0 && threadIdx.x == 0)
        out[0] = 0.0f;                             // safe: finish launches after

    __shared__ short FRsh[FPC * FRAG_SHORTS];      // 64 KB: B-frags of chunk

    const int tid  = threadIdx.x;
    const int lane = tid & 63;
    const int wave = __builtin_amdgcn_readfirstlane(tid >> 6);

    // ---- Fused split: stage this chunk's 2048 raw points -> B-frag LDS.
    //      Thread tid: points tid*4..tid*4+3 via 3 coalesced float4 loads. ----
    {
        const float* src = T + (size_t)tc * TPC * 3 + tid * 12;
        const f32x4 v0 = *(const f32x4*)(src + 0);
        const f32x4 v1 = *(const f32x4*)(src + 4);
        const f32x4 v2 = *(const f32x4*)(src + 8);
        const float px[4] = {v0.x, v0.w, v1.z, v2.y};
        const float py[4] = {v0.y, v1.x, v1.w, v2.z};
        const float pz[4] = {v0.z, v1.y, v2.x, v2.w};
        #pragma unroll
        for (int j = 0; j < 4; ++j) {
            const int p = tid * 4 + j;             // point within chunk
            const float x = px[j], y = py[j], z = pz[j];
            const ushort hx = bf16rne(x), hy = bf16rne(y), hz = bf16rne(z);
            const ushort lx = bf16rne(x - bf2f(hx));
            const ushort ly = bf16rne(y - bf2f(hy));
            const ushort lz = bf16rne(z - bf2f(hz));
            const float w = fmaf(x, x, fmaf(y, y, z * z));
            const ushort wh = bf16rne(w), wl = bf16rne(w - bf2f(wh));
            short* fb = FRsh + (p >> 5) * FRAG_SHORTS + (p & 31) * 8;
            *(bf16x8*)fb =
                (bf16x8){(short)hx, (short)hy, (short)hz, (short)hx,
                         (short)hy, (short)hz, (short)lx, (short)ly};
            *(bf16x8*)(fb + 256) =                 // k-group 1: lane 32+col
                (bf16x8){(short)lz, (short)lx, (short)ly, (short)lz,
                         (short)wh, (short)wl, (short)0, (short)0};
        }
    }

    // ---- 2 A-frags per wave (each wave owns 64 distinct queries). ----
    const int arow = lane & 31, kg = lane >> 5;
    const int qw = blockIdx.x * QPB + wave * 64;   // this wave's query base
    bf16x8 a[2];
    #pragma unroll
    for (int f = 0; f < 2; ++f) {
        const int q = qw + f * 32 + arow;
        const float x = Q[3 * q + 0], y = Q[3 * q + 1], z = Q[3 * q + 2];
        const float ux = -2.f * x, uy = -2.f * y, uz = -2.f * z;
        const ushort hx = bf16rne(ux), hy = bf16rne(uy), hz = bf16rne(uz);
        const ushort lx = bf16rne(ux - bf2f(hx));
        const ushort ly = bf16rne(uy - bf2f(hy));
        const ushort lz = bf16rne(uz - bf2f(hz));
        if (kg == 0)
            a[f] = (bf16x8){(short)hx, (short)hy, (short)hz, (short)lx,
                            (short)ly, (short)lz, (short)hx, (short)hy};
        else
            a[f] = (bf16x8){(short)hz, (short)lx, (short)ly, (short)lz,
                            (short)0x3f80, (short)0x3f80, (short)0, (short)0};
    }

    f32x16 mm0 = (f32x16)(FLT_MAX), mm1 = (f32x16)(FLT_MAX);
    const f32x16 zc = (f32x16)(0.f);

    __syncthreads();                               // chunk staged

    // ---- Sweep the 64 LDS frags, 2 per step, min3-merged (R15-proven). ----
    const short* rb = FRsh + lane * 8;
    for (int f2 = 0; f2 < FPC; f2 += 2) {
        const bf16x8 b0 = *(const bf16x8*)(rb + f2 * FRAG_SHORTS);
        const bf16x8 b1 = *(const bf16x8*)(rb + (f2 + 1) * FRAG_SHORTS);
        const f32x16 d00 = __builtin_amdgcn_mfma_f32_32x32x16_bf16(a[0], b0, zc, 0, 0, 0);
        const f32x16 d01 = __builtin_amdgcn_mfma_f32_32x32x16_bf16(a[0], b1, zc, 0, 0, 0);
        #pragma unroll
        for (int i = 0; i < 16; ++i)
            mm0[i] = fminf(fminf(d00[i], d01[i]), mm0[i]);   // -> v_min3_f32
        const f32x16 d10 = __builtin_amdgcn_mfma_f32_32x32x16_bf16(a[1], b0, zc, 0, 0, 0);
        const f32x16 d11 = __builtin_amdgcn_mfma_f32_32x32x16_bf16(a[1], b1, zc, 0, 0, 0);
        #pragma unroll
        for (int i = 0; i < 16; ++i)
            mm1[i] = fminf(fminf(d10[i], d11[i]), mm1[i]);
    }

    // ---- Cross-lane min over the 32 target-cols; write partials direct. ----
    float* pd = part2 + (size_t)blockIdx.y * NPTS + qw;   // [dir*8+tc][q]
    #pragma unroll
    for (int i = 0; i < 16; ++i) {
        float v0 = mm0[i], v1 = mm1[i];
        #pragma unroll
        for (int off = 1; off <= 16; off <<= 1) {
            v0 = fminf(v0, __shfl_xor(v0, off, 64));
            v1 = fminf(v1, __shfl_xor(v1, off, 64));
        }
        const int row = (i & 3) + 8 * (i >> 2) + 4 * kg;
        if ((lane & 31) == 0) {
            pd[row]      = v0;                     // frag 0: query qw+row
            pd[32 + row] = v1;                     // frag 1: query qw+32+row
        }
    }
}

// min over the 8 chunk-partials, add |q|^2, global sum.
__global__ __launch_bounds__(512) void cd_finish(const float* __restrict__ gt,
                                                 const float* __restrict__ gen,
                                                 const float* __restrict__ part2,
                                                 float* __restrict__ out) {
    const int t   = blockIdx.x * 512 + threadIdx.x;   // 0..32767
    const int dir = t >> 14;
    const int q   = t & (NPTS - 1);
    const float* __restrict__ Q = dir ? gen : gt;

    float m = FLT_MAX;
    #pragma unroll
    for (int tc = 0; tc < NTC; ++tc)
        m = fminf(m, part2[(size_t)(dir * NTC + tc) * NPTS + q]);
    const float x = Q[3 * q + 0], y = Q[3 * q + 1], z = Q[3 * q + 2];
    float v = m + fmaf(x, x, fmaf(y, y, z * z));

    #pragma unroll
    for (int off = 32; off > 0; off >>= 1) v += __shfl_down(v, off, 64);
    __shared__ float ws[8];
    const int lane = threadIdx.x & 63, w = threadIdx.x >> 6;
    if (lane == 0) ws[w] = v;
    __syncthreads();
    if (threadIdx.x == 0) {
        float s = 0.0f;
        #pragma unroll
        for (int i = 0; i < 8; ++i) s += ws[i];
        atomicAdd(out, s * (1.0f / (float)NPTS));
    }
}

extern "C" void kernel_launch(void* const* d_in, const int* in_sizes, int n_in,
                              void* d_out, int out_size, void* d_ws, size_t ws_size,
                              hipStream_t stream) {
    const float* gt  = (const float*)d_in[0];
    const float* gen = (const float*)d_in[1];
    float* part2     = (float*)d_ws;               // 16 x 16384 f32 = 1 MB
    float* out       = (float*)d_out;

    dim3 grid(NQB, NTC * 2);                       // 32 x 16 = 512 blocks
    cd_main<<<grid, 512, 0, stream>>>(gt, gen, part2, out);
    cd_finish<<<64, 512, 0, stream>>>(gt, gen, part2, out);
}

// Round 19
// 77.677 us; speedup vs baseline: 1.2143x; 1.0001x over previous
//
#include <hip/hip_runtime.h>
#include <float.h>

// Chamfer distance, fp32, N=M=16384 — R19: R17 base + s_setprio on MFMA.
//
// R18 post-mortem: hipLaunchCooperativeKernel silently no-ops under this
// harness's graph capture (absmax error == reference value -> output was
// the memset zero; kernel never ran). Cooperative grid sync is OFF the
// table; counter-based last-block-finish also impossible (d_ws re-poisoned
// every iteration, d_out has no spare slot). R19 reverts to the verified
// R17 2-kernel structure (77.7us, absmax 0.0) and tests the one remaining
// cheap lever as a single variable: s_setprio(1) around the MFMA cluster.
// Regime check (T5): after the staging barrier the 8 waves run barrier-
// free and drift out of phase -> role diversity exists (attn-like, +4-7%
// measured there), not GEMM-lockstep (null).
//
// Math (absmax 0.0, R7-R17): d = u.t + |t|^2 + |q|^2, u=-2q, 2-level bf16
// split, full product expansion in K=14 of 16:
//   k:      0..2     3..5     6..7+8   9..11    12 13
//   A:    uh(xyz)  ul(xyz)  uh(xyz)  ul(xyz)    1  1
//   B:    th(xyz)  th(xyz)  tl(xyz)  tl(xyz)   wh wl
// Layouts (guide §3, m74/m101): A row=lane&31, k=8*(lane>>5)+j; B col=
// lane&31; D col=lane&31, row=(reg&3)+8*(reg>>2)+4*(lane>>5).

#define NPTS 16384
constexpr int QPB   = 512;                // queries per block (64 per wave)
constexpr int NQB   = NPTS / QPB;         // 32 query-blocks per direction
constexpr int TPC   = 2048;               // targets per chunk
constexpr int NTC   = NPTS / TPC;         // 8 target chunks
constexpr int FPC   = TPC / 32;           // 64 frags per chunk (64KB LDS)
constexpr int FRAG_SHORTS = 512;          // 64 lane-slots x 8 bf16 = 1KB/frag

typedef float  f32x4  __attribute__((ext_vector_type(4)));
typedef float  f32x16 __attribute__((ext_vector_type(16)));
typedef short  bf16x8 __attribute__((ext_vector_type(8)));

__device__ inline ushort bf16rne(float f) {
    uint u = __float_as_uint(f);
    u += 0x7fff + ((u >> 16) & 1);        // round-to-nearest-even
    return (ushort)(u >> 16);
}
__device__ inline float bf2f(ushort h) { return __uint_as_float(((uint)h) << 16); }

__global__ __launch_bounds__(512, 2) void cd_main(const float* __restrict__ gt,
                                                  const float* __restrict__ gen,
                                                  float* __restrict__ part2,
                                                  float* __restrict__ out) {
    const int tc  = blockIdx.y & (NTC - 1);        // target chunk 0..7
    const int dir = blockIdx.y >> 3;               // 0: gt->gen, 1: gen->gt
    const float* __restrict__ Q = dir ? gen : gt;
    const float* __restrict__ T = dir ? gt : gen;  // opposite set

    if (blockIdx.x == 0 && blockIdx.y == 0 && threadIdx.x == 0)
        out[0] = 0.0f;                             // safe: finish launches after

    __shared__ short FRsh[FPC * FRAG_SHORTS];      // 64 KB: B-frags of chunk

    const int tid  = threadIdx.x;
    const int lane = tid & 63;
    const int wave = __builtin_amdgcn_readfirstlane(tid >> 6);

    // ---- Fused split: stage this chunk's 2048 raw points -> B-frag LDS.
    //      Thread tid: points tid*4..tid*4+3 via 3 coalesced float4 loads. ----
    {
        const float* src = T + (size_t)tc * TPC * 3 + tid * 12;
        const f32x4 v0 = *(const f32x4*)(src + 0);
        const f32x4 v1 = *(const f32x4*)(src + 4);
        const f32x4 v2 = *(const f32x4*)(src + 8);
        const float px[4] = {v0.x, v0.w, v1.z, v2.y};
        const float py[4] = {v0.y, v1.x, v1.w, v2.z};
        const float pz[4] = {v0.z, v1.y, v2.x, v2.w};
        #pragma unroll
        for (int j = 0; j < 4; ++j) {
            const int p = tid * 4 + j;             // point within chunk
            const float x = px[j], y = py[j], z = pz[j];
            const ushort hx = bf16rne(x), hy = bf16rne(y), hz = bf16rne(z);
            const ushort lx = bf16rne(x - bf2f(hx));
            const ushort ly = bf16rne(y - bf2f(hy));
            const ushort lz = bf16rne(z - bf2f(hz));
            const float w = fmaf(x, x, fmaf(y, y, z * z));
            const ushort wh = bf16rne(w), wl = bf16rne(w - bf2f(wh));
            short* fb = FRsh + (p >> 5) * FRAG_SHORTS + (p & 31) * 8;
            *(bf16x8*)fb =
                (bf16x8){(short)hx, (short)hy, (short)hz, (short)hx,
                         (short)hy, (short)hz, (short)lx, (short)ly};
            *(bf16x8*)(fb + 256) =                 // k-group 1: lane 32+col
                (bf16x8){(short)lz, (short)lx, (short)ly, (short)lz,
                         (short)wh, (short)wl, (short)0, (short)0};
        }
    }

    // ---- 2 A-frags per wave (each wave owns 64 distinct queries). ----
    const int arow = lane & 31, kg = lane >> 5;
    const int qw = blockIdx.x * QPB + wave * 64;   // this wave's query base
    bf16x8 a[2];
    #pragma unroll
    for (int f = 0; f < 2; ++f) {
        const int q = qw + f * 32 + arow;
        const float x = Q[3 * q + 0], y = Q[3 * q + 1], z = Q[3 * q + 2];
        const float ux = -2.f * x, uy = -2.f * y, uz = -2.f * z;
        const ushort hx = bf16rne(ux), hy = bf16rne(uy), hz = bf16rne(uz);
        const ushort lx = bf16rne(ux - bf2f(hx));
        const ushort ly = bf16rne(uy - bf2f(hy));
        const ushort lz = bf16rne(uz - bf2f(hz));
        if (kg == 0)
            a[f] = (bf16x8){(short)hx, (short)hy, (short)hz, (short)lx,
                            (short)ly, (short)lz, (short)hx, (short)hy};
        else
            a[f] = (bf16x8){(short)hz, (short)lx, (short)ly, (short)lz,
                            (short)0x3f80, (short)0x3f80, (short)0, (short)0};
    }

    f32x16 mm0 = (f32x16)(FLT_MAX), mm1 = (f32x16)(FLT_MAX);
    const f32x16 zc = (f32x16)(0.f);

    __syncthreads();                               // chunk staged

    // ---- Sweep the 64 LDS frags, 2 per step, min3-merged; setprio(1)
    //      around the MFMA cluster (single-variable change vs R17). ----
    const short* rb = FRsh + lane * 8;
    for (int f2 = 0; f2 < FPC; f2 += 2) {
        const bf16x8 b0 = *(const bf16x8*)(rb + f2 * FRAG_SHORTS);
        const bf16x8 b1 = *(const bf16x8*)(rb + (f2 + 1) * FRAG_SHORTS);
        __builtin_amdgcn_s_setprio(1);
        const f32x16 d00 = __builtin_amdgcn_mfma_f32_32x32x16_bf16(a[0], b0, zc, 0, 0, 0);
        const f32x16 d01 = __builtin_amdgcn_mfma_f32_32x32x16_bf16(a[0], b1, zc, 0, 0, 0);
        const f32x16 d10 = __builtin_amdgcn_mfma_f32_32x32x16_bf16(a[1], b0, zc, 0, 0, 0);
        const f32x16 d11 = __builtin_amdgcn_mfma_f32_32x32x16_bf16(a[1], b1, zc, 0, 0, 0);
        __builtin_amdgcn_s_setprio(0);
        #pragma unroll
        for (int i = 0; i < 16; ++i) {
            mm0[i] = fminf(fminf(d00[i], d01[i]), mm0[i]);   // -> v_min3_f32
            mm1[i] = fminf(fminf(d10[i], d11[i]), mm1[i]);
        }
    }

    // ---- Cross-lane min over the 32 target-cols; write partials direct. ----
    float* pd = part2 + (size_t)blockIdx.y * NPTS + qw;   // [dir*8+tc][q]
    #pragma unroll
    for (int i = 0; i < 16; ++i) {
        float v0 = mm0[i], v1 = mm1[i];
        #pragma unroll
        for (int off = 1; off <= 16; off <<= 1) {
            v0 = fminf(v0, __shfl_xor(v0, off, 64));
            v1 = fminf(v1, __shfl_xor(v1, off, 64));
        }
        const int row = (i & 3) + 8 * (i >> 2) + 4 * kg;
        if ((lane & 31) == 0) {
            pd[row]      = v0;                     // frag 0: query qw+row
            pd[32 + row] = v1;                     // frag 1: query qw+32+row
        }
    }
}

// min over the 8 chunk-partials, add |q|^2, global sum.
__global__ __launch_bounds__(512) void cd_finish(const float* __restrict__ gt,
                                                 const float* __restrict__ gen,
                                                 const float* __restrict__ part2,
                                                 float* __restrict__ out) {
    const int t   = blockIdx.x * 512 + threadIdx.x;   // 0..32767
    const int dir = t >> 14;
    const int q   = t & (NPTS - 1);
    const float* __restrict__ Q = dir ? gen : gt;

    float m = FLT_MAX;
    #pragma unroll
    for (int tc = 0; tc < NTC; ++tc)
        m = fminf(m, part2[(size_t)(dir * NTC + tc) * NPTS + q]);
    const float x = Q[3 * q + 0], y = Q[3 * q + 1], z = Q[3 * q + 2];
    float v = m + fmaf(x, x, fmaf(y, y, z * z));

    #pragma unroll
    for (int off = 32; off > 0; off >>= 1) v += __shfl_down(v, off, 64);
    __shared__ float ws[8];
    const int lane = threadIdx.x & 63, w = threadIdx.x >> 6;
    if (lane == 0) ws[w] = v;
    __syncthreads();
    if (threadIdx.x == 0) {
        float s = 0.0f;
        #pragma unroll
        for (int i = 0; i < 8; ++i) s += ws[i];
        atomicAdd(out, s * (1.0f / (float)NPTS));
    }
}

extern "C" void kernel_launch(void* const* d_in, const int* in_sizes, int n_in,
                              void* d_out, int out_size, void* d_ws, size_t ws_size,
                              hipStream_t stream) {
    const float* gt  = (const float*)d_in[0];
    const float* gen = (const float*)d_in[1];
    float* part2     = (float*)d_ws;               // 16 x 16384 f32 = 1 MB
    float* out       = (float*)d_out;

    dim3 grid(NQB, NTC * 2);                       // 32 x 16 = 512 blocks
    cd_main<<<grid, 512, 0, stream>>>(gt, gen, part2, out);
    cd_finish<<<64, 512, 0, stream>>>(gt, gen, part2, out);
}